// Round 1
// baseline (299.478 us; speedup 1.0000x reference)
//
#include <hip/hip_runtime.h>

// SparseActivation: per row of D=2048 fp32, keep top K=204 by |x|, scale by D/K.
// One workgroup (256 threads) per row; exact 31-bit radix select on abs bits.

constexpr int D_DIM = 2048;
constexpr int K_SEL = 204;     // int(2048 * 0.1)
constexpr int NT    = 256;

__global__ __launch_bounds__(NT) void sparse_topk_kernel(const float* __restrict__ x,
                                                         float* __restrict__ out) {
    const long long row = blockIdx.x;
    const float* xr = x + row * D_DIM;
    float* outr = out + row * D_DIM;
    const int t = threadIdx.x;

    __shared__ unsigned hist[256];
    __shared__ unsigned sbuf[256];
    __shared__ unsigned s_bucket, s_want, s_neq;
    __shared__ unsigned ubits[D_DIM];        // only used on rare tie path
    __shared__ unsigned char eqsel[D_DIM];   // only used on rare tie path

    // Load row: thread t owns indices [4t,4t+4) and [1024+4t, 1024+4t+4)
    const float4 v0 = reinterpret_cast<const float4*>(xr)[t];
    const float4 v1 = reinterpret_cast<const float4*>(xr)[NT + t];
    float vv[8] = {v0.x, v0.y, v0.z, v0.w, v1.x, v1.y, v1.z, v1.w};
    unsigned u[8];
#pragma unroll
    for (int e = 0; e < 8; ++e) u[e] = __float_as_uint(vv[e]) & 0x7fffffffu;

    // Radix select: find T = K-th largest abs-bit pattern in the row.
    // Digits (MSB-first): bits[30:23], [22:15], [14:7], [6:0].
    unsigned want = K_SEL;   // how many still to select within current prefix
    unsigned prefix = 0;     // chosen high bits so far

#pragma unroll
    for (int p = 0; p < 4; ++p) {
        const int sh = (p == 0) ? 23 : (p == 1) ? 15 : (p == 2) ? 7 : 0;
        const int psh = (p == 1) ? 23 : (p == 2) ? 15 : 7;  // prev-pass shift
        const unsigned dmask = (p == 3) ? 0x7Fu : 0xFFu;

        hist[t] = 0;
        __syncthreads();
#pragma unroll
        for (int e = 0; e < 8; ++e) {
            const bool active = (p == 0) || ((u[e] >> psh) == prefix);
            if (active) atomicAdd(&hist[(u[e] >> sh) & dmask], 1u);
        }
        __syncthreads();

        // Suffix sum over buckets (descending order): sbuf[b] = sum hist[b..255]
        sbuf[t] = hist[t];
        __syncthreads();
#pragma unroll
        for (int off = 1; off < 256; off <<= 1) {
            const unsigned add = (t + off < 256) ? sbuf[t + off] : 0u;
            __syncthreads();
            sbuf[t] += add;
            __syncthreads();
        }
        const unsigned smine = sbuf[t];
        const unsigned snext = (t < 255) ? sbuf[t + 1] : 0u;
        // unique t with suffix[t] >= want > suffix[t+1]
        if (snext < want && want <= smine) {
            s_bucket = t;
            s_want = want - snext;
            s_neq = hist[t];
        }
        __syncthreads();
        const unsigned b = s_bucket;
        want = s_want;
        prefix = (p == 0) ? b : ((prefix << ((p == 3) ? 7 : 8)) | b);
        __syncthreads();  // all reads of s_*/hist done before next pass zeroes
    }

    const unsigned Tv = prefix;   // exact K-th largest abs bits
    const unsigned r = want;      // how many ==Tv elements to keep
    const unsigned neq = s_neq;   // total ==Tv elements

    // Rare tie path: more equals than we may keep -> keep lowest indices first
    const bool rare = (neq > r);
    if (rare) {
#pragma unroll
        for (int e = 0; e < 4; ++e) ubits[4 * t + e] = u[e];
#pragma unroll
        for (int e = 0; e < 4; ++e) ubits[1024 + 4 * t + e] = u[4 + e];
        __syncthreads();
        if (t == 0) {
            unsigned cnt = 0;
            for (int i = 0; i < D_DIM; ++i) {
                const bool eq = (ubits[i] == Tv);
                eqsel[i] = (eq && cnt < r) ? (unsigned char)1 : (unsigned char)0;
                cnt += eq ? 1u : 0u;
            }
        }
        __syncthreads();
    }

    const float scale = 2048.0f / 204.0f;
    float ov[8];
    if (!rare) {
#pragma unroll
        for (int e = 0; e < 8; ++e) ov[e] = (u[e] >= Tv) ? vv[e] * scale : 0.0f;
    } else {
#pragma unroll
        for (int e = 0; e < 8; ++e) {
            const int idx = (e < 4) ? (4 * t + e) : (1024 + 4 * t + (e - 4));
            const bool sel = (u[e] > Tv) || ((u[e] == Tv) && eqsel[idx]);
            ov[e] = sel ? vv[e] * scale : 0.0f;
        }
    }
    const float4 o0 = make_float4(ov[0], ov[1], ov[2], ov[3]);
    const float4 o1 = make_float4(ov[4], ov[5], ov[6], ov[7]);
    reinterpret_cast<float4*>(outr)[t] = o0;
    reinterpret_cast<float4*>(outr)[NT + t] = o1;
}

extern "C" void kernel_launch(void* const* d_in, const int* in_sizes, int n_in,
                              void* d_out, int out_size, void* d_ws, size_t ws_size,
                              hipStream_t stream) {
    const float* x = (const float*)d_in[0];
    float* out = (float*)d_out;
    const int rows = in_sizes[0] / D_DIM;  // 4*4096 = 16384
    sparse_topk_kernel<<<rows, NT, 0, stream>>>(x, out);
}

// Round 2
// 244.906 us; speedup vs baseline: 1.2228x; 1.2228x over previous
//
#include <hip/hip_runtime.h>

// SparseActivation: per row of D=2048 fp32, keep top K=204 by |x|, scale by D/K.
// One WAVE (64 lanes) per row, 32 elements/lane in registers.
// Exact K-th largest via 31-step bitwise binary search using ballot+popcount
// (no LDS, no barriers, no atomics). Exact lowest-index-first tie-break.

constexpr int D_DIM = 2048;
constexpr int K_SEL = 204;     // int(2048 * 0.1)
constexpr int NT    = 256;     // 4 waves/block, one row per wave
constexpr int EPL   = 32;      // elements per lane

__global__ __launch_bounds__(NT) void sparse_topk_kernel(const float* __restrict__ x,
                                                         float* __restrict__ out) {
    const int wave = threadIdx.x >> 6;
    const int lane = threadIdx.x & 63;
    const long long row = (long long)blockIdx.x * 4 + wave;
    const float* xr = x + row * D_DIM;
    float* outr = out + row * D_DIM;

    // Element (b, lane, e): global index = 256*b + 4*lane + e, j = 4*b + e.
    float v[EPL];
    unsigned u[EPL];
    const float4* xp = reinterpret_cast<const float4*>(xr);
#pragma unroll
    for (int b = 0; b < 8; ++b) {
        const float4 f = xp[b * 64 + lane];
        v[4 * b + 0] = f.x; v[4 * b + 1] = f.y;
        v[4 * b + 2] = f.z; v[4 * b + 3] = f.w;
    }
#pragma unroll
    for (int j = 0; j < EPL; ++j) u[j] = __float_as_uint(v[j]) & 0x7fffffffu;

    // T = max value such that count(u >= T) >= K  ==  exact K-th largest abs bits.
    unsigned T = 0u;
    for (int bit = 30; bit >= 0; --bit) {
        const unsigned test = T | (1u << bit);
        int cnt = 0;
#pragma unroll
        for (int j = 0; j < EPL; ++j)
            cnt += __popcll(__ballot(u[j] >= test));
        if (cnt >= K_SEL) T = test;   // wave-uniform scalar update
    }

    // Boundary bookkeeping.
    int cnt_gt = 0;
#pragma unroll
    for (int j = 0; j < EPL; ++j)
        cnt_gt += __popcll(__ballot(u[j] > T));
    int neq = 0;
#pragma unroll
    for (int j = 0; j < EPL; ++j)
        neq += __popcll(__ballot(u[j] == T));
    const int r = K_SEL - cnt_gt;     // equals to keep (1 <= r <= neq)

    const float scale = 2048.0f / 204.0f;

    if (neq == r) {
        // Common path: keep everything >= T.
#pragma unroll
        for (int j = 0; j < EPL; ++j) v[j] = (u[j] >= T) ? v[j] * scale : 0.0f;
    } else {
        // Rare tie path: among ==T, keep the r with lowest global index
        // (matches lax.top_k stability). Rank via equality ballots.
        const unsigned long long lt = (lane == 0) ? 0ull : (~0ull >> (64 - lane));
        int base = 0;  // equals in blocks b' < b
        for (int b = 0; b < 8; ++b) {
            unsigned long long m[4];
#pragma unroll
            for (int e = 0; e < 4; ++e) m[e] = __ballot(u[4 * b + e] == T);
            int cm = 0;  // equals in this block from lanes < lane (any e)
#pragma unroll
            for (int e = 0; e < 4; ++e) cm += __popcll(m[e] & lt);
            int partial = 0;  // equals in this block, same lane, e' < e
#pragma unroll
            for (int e = 0; e < 4; ++e) {
                const int j = 4 * b + e;
                const int rank = base + cm + partial;
                const bool eq = (u[j] == T);
                const bool sel = (u[j] > T) || (eq && rank < r);
                v[j] = sel ? v[j] * scale : 0.0f;
                partial += (int)((m[e] >> lane) & 1ull);
            }
#pragma unroll
            for (int e = 0; e < 4; ++e) base += __popcll(m[e]);
        }
    }

    float4* op = reinterpret_cast<float4*>(outr);
#pragma unroll
    for (int b = 0; b < 8; ++b)
        op[b * 64 + lane] = make_float4(v[4 * b + 0], v[4 * b + 1],
                                        v[4 * b + 2], v[4 * b + 3]);
}

extern "C" void kernel_launch(void* const* d_in, const int* in_sizes, int n_in,
                              void* d_out, int out_size, void* d_ws, size_t ws_size,
                              hipStream_t stream) {
    const float* x = (const float*)d_in[0];
    float* out = (float*)d_out;
    const int rows = in_sizes[0] / D_DIM;            // 16384
    sparse_topk_kernel<<<rows / 4, NT, 0, stream>>>(x, out);
}